// Round 2
// baseline (4841.159 us; speedup 1.0000x reference)
//
#include <hip/hip_runtime.h>
#include <hip/hip_fp16.h>

#define H 512
#define T 2048
#define B 64

union U4H { uint4 u; __half2 h[4]; };

// Repack W (fp32 [512][512]) into f16 pairs in the exact per-thread consumption
// layout: ws[ (j*8+q)*512 + tid ] = uint4 of 4 __half2 pairs =
//   W[row][col0..col0+7] with row = (tid/8)*8 + j, col0 = (tid%8)*64 + q*8.
__global__ void prep_kernel(const float* __restrict__ W, uint4* __restrict__ ws) {
    int f = blockIdx.x * 256 + threadIdx.x;      // 0..32767
    int t = f & 511;
    int qj = f >> 9;                              // 0..63
    int q = qj & 7;
    int j = qj >> 3;                              // 0..7
    int rg = t >> 3, c2 = t & 7;
    int row = rg * 8 + j;
    int col0 = c2 * 64 + q * 8;
    const float4* src = reinterpret_cast<const float4*>(W + row * H + col0);
    float4 lo = src[0];
    float4 hi = src[1];
    U4H pk;
    pk.h[0] = __floats2half2_rn(lo.x, lo.y);
    pk.h[1] = __floats2half2_rn(lo.z, lo.w);
    pk.h[2] = __floats2half2_rn(hi.x, hi.y);
    pk.h[3] = __floats2half2_rn(hi.z, hi.w);
    ws[f] = pk.u;
}

// One workgroup per batch element. 512 threads = 8 waves.
// thread tid: rg = tid/8 (row group: rows rg*8+j, j=0..7), c2 = tid%8 (cols c2*64..+63).
// Rows j=0..5 of W live in 192 VGPRs; rows j=6,7 streamed from L2 every step.
// After the c2 recursive-halving reduction, lane l holds the full dot for
// row (tid& ~7) + (l&7) == tid, so bias/W0/output indexing is simply [tid].
__global__ __launch_bounds__(512, 2) void rnn_kernel(
        const float* __restrict__ x, const float* __restrict__ h0,
        const float* __restrict__ W0, const float* __restrict__ b0,
        const float* __restrict__ bv, const uint4* __restrict__ ws,
        float* __restrict__ out)
{
    const int b = blockIdx.x;
    const int tid = threadIdx.x;
    const int l = tid & 63;
    const int c2 = tid & 7;

    __shared__ float xs[T];                      // staged x[b][:]
    __shared__ uint4 h2u[2][H / 8];              // h as f16, double-buffered

    for (int i = tid; i < T; i += 512) xs[i] = x[b * T + i];

    uint4 wreg[48];                              // rows j=0..5, 8 q-chunks each
#pragma unroll
    for (int i = 0; i < 48; ++i) wreg[i] = ws[i * 512 + tid];

    const uint4* w6p = ws + 48 * 512 + tid;      // row j=6 stream base
    const uint4* w7p = ws + 56 * 512 + tid;      // row j=7 stream base

    const float bb = b0[tid] + bv[tid];
    const float w0r = W0[tid];

    reinterpret_cast<__half*>(&h2u[0][0])[tid] = __float2half(h0[b * H + tid]);
    __syncthreads();

    float* yout = out + (size_t)b * T * H;
    float th = 0.f;

    for (int t = 0; t < T; ++t) {
        const int p = t & 1;
        const uint4* hb = &h2u[p][c2 * 8];

        __half2 a2[8];
#pragma unroll
        for (int j = 0; j < 8; ++j) a2[j] = __float2half2_rn(0.f);

        U4H hc, w6c, w7c;
        hc.u  = hb[0];
        w6c.u = w6p[0];
        w7c.u = w7p[0];
#pragma unroll
        for (int q = 0; q < 8; ++q) {
            U4H hn, w6n, w7n;
            if (q < 7) {                          // 1-deep prefetch of next chunk
                hn.u  = hb[q + 1];
                w6n.u = w6p[(q + 1) * 512];
                w7n.u = w7p[(q + 1) * 512];
            }
#pragma unroll
            for (int j = 0; j < 6; ++j) {
                const U4H* wp = reinterpret_cast<const U4H*>(&wreg[j * 8 + q]);
#pragma unroll
                for (int pi = 0; pi < 4; ++pi)
                    a2[j] = __hfma2(wp->h[pi], hc.h[pi], a2[j]);
            }
#pragma unroll
            for (int pi = 0; pi < 4; ++pi) a2[6] = __hfma2(w6c.h[pi], hc.h[pi], a2[6]);
#pragma unroll
            for (int pi = 0; pi < 4; ++pi) a2[7] = __hfma2(w7c.h[pi], hc.h[pi], a2[7]);
            if (q < 7) { hc = hn; w6c = w6n; w7c = w7n; }
        }

        float acc[8];
#pragma unroll
        for (int j = 0; j < 8; ++j)
            acc[j] = __low2float(a2[j]) + __high2float(a2[j]);

        // recursive-halving reduce over the 8 c2 lanes (masks 4,2,1).
        // lane keeps j-indices whose bits match its own; ends with j = l&7.
        const bool g4 = (l & 4) != 0, g2 = (l & 2) != 0, g1 = (l & 1) != 0;
        float k[4];
#pragma unroll
        for (int i = 0; i < 4; ++i) {
            float send = g4 ? acc[i] : acc[i + 4];
            float got = __shfl_xor(send, 4, 64);
            k[i] = (g4 ? acc[i + 4] : acc[i]) + got;
        }
        float kk[2];
#pragma unroll
        for (int i = 0; i < 2; ++i) {
            float send = g2 ? k[i] : k[i + 2];
            float got = __shfl_xor(send, 2, 64);
            kk[i] = (g2 ? k[i + 2] : k[i]) + got;
        }
        float fin;
        {
            float send = g1 ? kk[0] : kk[1];
            float got = __shfl_xor(send, 1, 64);
            fin = (g1 ? kk[1] : kk[0]) + got;
        }

        float z = fmaf(xs[t], w0r, fin + bb);
        float e = __expf(2.f * z);
        th = 1.f - 2.f / (e + 1.f);               // tanh(z); saturates correctly

        yout[(size_t)t * H + tid] = th;
        reinterpret_cast<__half*>(&h2u[p ^ 1][0])[tid] = __float2half(th);
        // barrier WITHOUT vmcnt(0): don't drain the y store each step.
        asm volatile("s_waitcnt lgkmcnt(0)\n\ts_barrier" ::: "memory");
    }

    out[(size_t)B * T * H + (size_t)b * H + tid] = th;
}

extern "C" void kernel_launch(void* const* d_in, const int* in_sizes, int n_in,
                              void* d_out, int out_size, void* d_ws, size_t ws_size,
                              hipStream_t stream) {
    const float* x  = (const float*)d_in[0];
    const float* h0 = (const float*)d_in[1];
    const float* W0 = (const float*)d_in[2];
    const float* b0 = (const float*)d_in[3];
    const float* W  = (const float*)d_in[4];
    const float* bv = (const float*)d_in[5];
    float* out = (float*)d_out;
    uint4* ws = (uint4*)d_ws;

    prep_kernel<<<128, 256, 0, stream>>>(W, ws);
    rnn_kernel<<<B, 512, 0, stream>>>(x, h0, W0, b0, bv, ws, out);
}